// Round 1
// baseline (1278.286 us; speedup 1.0000x reference)
//
#include <hip/hip_runtime.h>
#include <cstdint>
#include <cmath>

#define N0c 247808
#define N1c 22528
#define NBc 2048
#define E0c 225280
#define E1c 20480
#define Cc  256

// One wave (64 lanes) per edge: lane i handles channels [4i, 4i+4).
__global__ void scatter_edges(const float* __restrict__ x,
                              const int* __restrict__ src,
                              const int* __restrict__ dst,
                              const int* __restrict__ eid,
                              const float* __restrict__ ew,
                              float* __restrict__ agg,
                              float* __restrict__ cnt,
                              int E) {
    int gid  = blockIdx.x * blockDim.x + threadIdx.x;
    int e    = gid >> 6;
    int lane = threadIdx.x & 63;
    if (e >= E) return;
    int s = src[e];
    int d = dst[e];
    float w = ew[eid[e]];
    float4 v = ((const float4*)(x + (size_t)s * Cc))[lane];
    float* ar = agg + (size_t)d * Cc + lane * 4;
    atomicAdd(ar + 0, v.x * w);
    atomicAdd(ar + 1, v.y * w);
    atomicAdd(ar + 2, v.z * w);
    atomicAdd(ar + 3, v.w * w);
    if (lane == 0) atomicAdd(cnt + d, 1.0f);
}

// out[i][j] = sum_k mean[i][k]*Wrel[k][j] + sum_k root[i][k]*Wroot[k][j] + b[j]
// Block: 256 threads, tile 32 rows x 256 cols. Thread: 8 rows x 4 cols acc.
// Within a wave, mg is constant -> LDS A reads are same-address broadcasts
// (conflict-free); W loads are 1KB/wave coalesced.
template <bool RELU>
__global__ __launch_bounds__(256) void gemm_fused(
    const float* __restrict__ agg, const float* __restrict__ cnt,
    const float* __restrict__ root,
    const float* __restrict__ Wrel, const float* __restrict__ Wroot,
    const float* __restrict__ bias, float* __restrict__ out) {
    __shared__ float AsmM[32 * Cc];
    __shared__ float AsmR[32 * Cc];
    const int t = threadIdx.x;
    const int base = blockIdx.x * 32;

    // Stage mean rows (agg/cnt) and root rows into LDS; coalesced, conflict-free.
    for (int idx = t; idx < 32 * Cc; idx += 256) {
        int r = idx >> 8;
        int k = idx & 255;
        int grow = base + r;
        float cv  = cnt[grow];
        float inv = 1.0f / fmaxf(cv, 1.0f);
        AsmM[idx] = agg[(size_t)grow * Cc + k] * inv;
        AsmR[idx] = root[(size_t)grow * Cc + k];
    }
    __syncthreads();

    const int jg = t & 63;      // lane -> column group
    const int mg = t >> 6;      // wave -> row group
    const int j0 = jg * 4;
    const int r0 = mg * 8;

    float acc[8][4];
#pragma unroll
    for (int r = 0; r < 8; r++)
#pragma unroll
        for (int c = 0; c < 4; c++) acc[r][c] = 0.0f;

    for (int kc = 0; kc < Cc; kc += 4) {
        float4 wr[4], wo[4];
#pragma unroll
        for (int kk = 0; kk < 4; kk++) {
            wr[kk] = *(const float4*)(Wrel  + (kc + kk) * Cc + j0);
            wo[kk] = *(const float4*)(Wroot + (kc + kk) * Cc + j0);
        }
#pragma unroll
        for (int r = 0; r < 8; r++) {
            float4 am = *(const float4*)(AsmM + (r0 + r) * Cc + kc);
            float4 ar = *(const float4*)(AsmR + (r0 + r) * Cc + kc);
            acc[r][0] += am.x * wr[0].x + am.y * wr[1].x + am.z * wr[2].x + am.w * wr[3].x
                       + ar.x * wo[0].x + ar.y * wo[1].x + ar.z * wo[2].x + ar.w * wo[3].x;
            acc[r][1] += am.x * wr[0].y + am.y * wr[1].y + am.z * wr[2].y + am.w * wr[3].y
                       + ar.x * wo[0].y + ar.y * wo[1].y + ar.z * wo[2].y + ar.w * wo[3].y;
            acc[r][2] += am.x * wr[0].z + am.y * wr[1].z + am.z * wr[2].z + am.w * wr[3].z
                       + ar.x * wo[0].z + ar.y * wo[1].z + ar.z * wo[2].z + ar.w * wo[3].z;
            acc[r][3] += am.x * wr[0].w + am.y * wr[1].w + am.z * wr[2].w + am.w * wr[3].w
                       + ar.x * wo[0].w + ar.y * wo[1].w + ar.z * wo[2].w + ar.w * wo[3].w;
        }
    }

    float4 bv = *(const float4*)(bias + j0);
#pragma unroll
    for (int r = 0; r < 8; r++) {
        float4 o;
        o.x = acc[r][0] + bv.x;
        o.y = acc[r][1] + bv.y;
        o.z = acc[r][2] + bv.z;
        o.w = acc[r][3] + bv.w;
        if (RELU) {
            o.x = fmaxf(o.x, 0.0f);
            o.y = fmaxf(o.y, 0.0f);
            o.z = fmaxf(o.z, 0.0f);
            o.w = fmaxf(o.w, 0.0f);
        }
        *(float4*)(out + (size_t)(base + r0 + r) * Cc + j0) = o;
    }
}

// One wave per row; lane holds 4 channels.
__global__ void log_softmax_k(const float* __restrict__ in, float* __restrict__ out) {
    int gid  = blockIdx.x * blockDim.x + threadIdx.x;
    int row  = gid >> 6;
    int lane = threadIdx.x & 63;
    float4 v = ((const float4*)(in + (size_t)row * Cc))[lane];
    float m = fmaxf(fmaxf(v.x, v.y), fmaxf(v.z, v.w));
#pragma unroll
    for (int o = 32; o; o >>= 1) m = fmaxf(m, __shfl_xor(m, o));
    float s = expf(v.x - m) + expf(v.y - m) + expf(v.z - m) + expf(v.w - m);
#pragma unroll
    for (int o = 32; o; o >>= 1) s += __shfl_xor(s, o);
    float lse = m + logf(s);
    float4 o4;
    o4.x = v.x - lse; o4.y = v.y - lse; o4.z = v.z - lse; o4.w = v.w - lse;
    ((float4*)(out + (size_t)row * Cc))[lane] = o4;
}

extern "C" void kernel_launch(void* const* d_in, const int* in_sizes, int n_in,
                              void* d_out, int out_size, void* d_ws, size_t ws_size,
                              hipStream_t stream) {
    const float* x     = (const float*)d_in[0];
    const int*   src0  = (const int*)d_in[1];
    const int*   dst0  = (const int*)d_in[2];
    const int*   eid0  = (const int*)d_in[3];
    const int*   src1  = (const int*)d_in[4];
    const int*   dst1  = (const int*)d_in[5];
    const int*   eid1  = (const int*)d_in[6];
    const float* ew    = (const float*)d_in[7];
    const float* Wrel0 = (const float*)d_in[8];
    const float* b0    = (const float*)d_in[9];
    const float* Wroot0= (const float*)d_in[10];
    const float* Wrel1 = (const float*)d_in[11];
    const float* b1    = (const float*)d_in[12];
    const float* Wroot1= (const float*)d_in[13];

    float* ws   = (float*)d_ws;
    float* agg0 = ws;                              // N1*C
    float* cnt0 = agg0 + (size_t)N1c * Cc;         // N1
    float* agg1 = cnt0 + N1c;                      // NB*C
    float* cnt1 = agg1 + (size_t)NBc * Cc;         // NB
    float* h    = cnt1 + NBc;                      // N1*C

    size_t zeroN = (size_t)N1c * Cc + N1c + (size_t)NBc * Cc + NBc;
    hipMemsetAsync(agg0, 0, zeroN * sizeof(float), stream);

    // Layer 0 aggregation: one wave per edge.
    {
        int waves  = E0c;
        int blocks = (waves * 64 + 255) / 256;
        scatter_edges<<<blocks, 256, 0, stream>>>(x, src0, dst0, eid0, ew, agg0, cnt0, E0c);
    }
    // h = relu(mean0 @ Wrel0 + b0 + x[:N1] @ Wroot0)
    gemm_fused<true><<<N1c / 32, 256, 0, stream>>>(agg0, cnt0, x, Wrel0, Wroot0, b0, h);

    // Layer 1 aggregation over h.
    {
        int waves  = E1c;
        int blocks = (waves * 64 + 255) / 256;
        scatter_edges<<<blocks, 256, 0, stream>>>(h, src1, dst1, eid1, ew, agg1, cnt1, E1c);
    }
    // out2 = mean1 @ Wrel1 + b1 + h[:NB] @ Wroot1
    float* out2 = (float*)d_out;
    gemm_fused<false><<<NBc / 32, 256, 0, stream>>>(agg1, cnt1, h, Wrel1, Wroot1, b1, out2);

    // log_softmax rows
    log_softmax_k<<<(NBc * 64) / 256, 256, 0, stream>>>(out2, out2 + (size_t)NBc * Cc);
}

// Round 2
// 596.987 us; speedup vs baseline: 2.1412x; 2.1412x over previous
//
#include <hip/hip_runtime.h>
#include <cstdint>
#include <cmath>

#define N0c 247808
#define N1c 22528
#define NBc 2048
#define E0c 225280
#define E1c 20480
#define Cc  256

// ---------- CSR build: degree count ----------
__global__ void count_deg(const int* __restrict__ dst, int* __restrict__ deg, int E) {
    int e = blockIdx.x * blockDim.x + threadIdx.x;
    if (e < E) atomicAdd(&deg[dst[e]], 1);
}

// ---------- CSR build: single-block exclusive scan ----------
// deg (in, also rewritten as cur) -> off (exclusive prefix), cur[i] = off[i]
__global__ __launch_bounds__(1024) void scan_kernel(int* __restrict__ deg,
                                                    int* __restrict__ off,
                                                    int n) {
    __shared__ int buf[1024];
    __shared__ int carry_s;
    int t = threadIdx.x;
    if (t == 0) carry_s = 0;
    __syncthreads();
    for (int base = 0; base < n; base += 1024) {
        int i = base + t;
        int v = (i < n) ? deg[i] : 0;
        buf[t] = v;
        __syncthreads();
        for (int o = 1; o < 1024; o <<= 1) {
            int add = (t >= o) ? buf[t - o] : 0;
            __syncthreads();
            buf[t] += add;
            __syncthreads();
        }
        int carry = carry_s;
        int exc = carry + buf[t] - v;
        if (i < n) { off[i] = exc; deg[i] = exc; }  // deg becomes "cur"
        __syncthreads();
        if (t == 1023) carry_s = carry + buf[1023];
        __syncthreads();
    }
    if (t == 0) off[n] = carry_s;
}

// ---------- CSR build: scatter edge payloads into sorted slots ----------
__global__ void fill_edges(const int* __restrict__ src, const int* __restrict__ dst,
                           const int* __restrict__ eid, const float* __restrict__ ew,
                           int* __restrict__ cur, int* __restrict__ srcs,
                           float* __restrict__ wsr, int E) {
    int e = blockIdx.x * blockDim.x + threadIdx.x;
    if (e < E) {
        int p = atomicAdd(&cur[dst[e]], 1);
        srcs[p] = src[e];
        wsr[p] = ew[eid[e]];
    }
}

// ---------- Gather-side mean aggregation: one wave per dst row ----------
__global__ __launch_bounds__(256) void gather_mean(const float* __restrict__ x,
                                                   const int* __restrict__ off,
                                                   const int* __restrict__ srcs,
                                                   const float* __restrict__ wsr,
                                                   float* __restrict__ mean,
                                                   int nrows) {
    int wid  = (blockIdx.x * blockDim.x + threadIdx.x) >> 6;
    int lane = threadIdx.x & 63;
    if (wid >= nrows) return;
    int s = off[wid], e = off[wid + 1];
    float4 acc = make_float4(0.f, 0.f, 0.f, 0.f);
    int i = s;
    for (; i + 1 < e; i += 2) {   // 2 independent row loads in flight
        int   sid0 = srcs[i],   sid1 = srcs[i + 1];
        float w0   = wsr[i],    w1   = wsr[i + 1];
        float4 v0 = ((const float4*)(x + (size_t)sid0 * Cc))[lane];
        float4 v1 = ((const float4*)(x + (size_t)sid1 * Cc))[lane];
        acc.x += w0 * v0.x + w1 * v1.x;
        acc.y += w0 * v0.y + w1 * v1.y;
        acc.z += w0 * v0.z + w1 * v1.z;
        acc.w += w0 * v0.w + w1 * v1.w;
    }
    if (i < e) {
        int sid = srcs[i];
        float w = wsr[i];
        float4 v = ((const float4*)(x + (size_t)sid * Cc))[lane];
        acc.x += w * v.x; acc.y += w * v.y; acc.z += w * v.z; acc.w += w * v.w;
    }
    float inv = 1.0f / fmaxf((float)(e - s), 1.0f);
    acc.x *= inv; acc.y *= inv; acc.z *= inv; acc.w *= inv;
    ((float4*)(mean + (size_t)wid * Cc))[lane] = acc;
}

// out[i][j] = sum_k mean[i][k]*Wrel[k][j] + sum_k root[i][k]*Wroot[k][j] + b[j]
template <bool RELU>
__global__ __launch_bounds__(256) void gemm_fused(
    const float* __restrict__ mean,
    const float* __restrict__ root,
    const float* __restrict__ Wrel, const float* __restrict__ Wroot,
    const float* __restrict__ bias, float* __restrict__ out) {
    __shared__ float AsmM[32 * Cc];
    __shared__ float AsmR[32 * Cc];
    const int t = threadIdx.x;
    const int base = blockIdx.x * 32;

    for (int idx = t; idx < 32 * Cc; idx += 256) {
        int r = idx >> 8;
        int k = idx & 255;
        int grow = base + r;
        AsmM[idx] = mean[(size_t)grow * Cc + k];
        AsmR[idx] = root[(size_t)grow * Cc + k];
    }
    __syncthreads();

    const int jg = t & 63;
    const int mg = t >> 6;
    const int j0 = jg * 4;
    const int r0 = mg * 8;

    float acc[8][4];
#pragma unroll
    for (int r = 0; r < 8; r++)
#pragma unroll
        for (int c = 0; c < 4; c++) acc[r][c] = 0.0f;

    for (int kc = 0; kc < Cc; kc += 4) {
        float4 wr[4], wo[4];
#pragma unroll
        for (int kk = 0; kk < 4; kk++) {
            wr[kk] = *(const float4*)(Wrel  + (kc + kk) * Cc + j0);
            wo[kk] = *(const float4*)(Wroot + (kc + kk) * Cc + j0);
        }
#pragma unroll
        for (int r = 0; r < 8; r++) {
            float4 am = *(const float4*)(AsmM + (r0 + r) * Cc + kc);
            float4 ar = *(const float4*)(AsmR + (r0 + r) * Cc + kc);
            acc[r][0] += am.x * wr[0].x + am.y * wr[1].x + am.z * wr[2].x + am.w * wr[3].x
                       + ar.x * wo[0].x + ar.y * wo[1].x + ar.z * wo[2].x + ar.w * wo[3].x;
            acc[r][1] += am.x * wr[0].y + am.y * wr[1].y + am.z * wr[2].y + am.w * wr[3].y
                       + ar.x * wo[0].y + ar.y * wo[1].y + ar.z * wo[2].y + ar.w * wo[3].y;
            acc[r][2] += am.x * wr[0].z + am.y * wr[1].z + am.z * wr[2].z + am.w * wr[3].z
                       + ar.x * wo[0].z + ar.y * wo[1].z + ar.z * wo[2].z + ar.w * wo[3].z;
            acc[r][3] += am.x * wr[0].w + am.y * wr[1].w + am.z * wr[2].w + am.w * wr[3].w
                       + ar.x * wo[0].w + ar.y * wo[1].w + ar.z * wo[2].w + ar.w * wo[3].w;
        }
    }

    float4 bv = *(const float4*)(bias + j0);
#pragma unroll
    for (int r = 0; r < 8; r++) {
        float4 o;
        o.x = acc[r][0] + bv.x;
        o.y = acc[r][1] + bv.y;
        o.z = acc[r][2] + bv.z;
        o.w = acc[r][3] + bv.w;
        if (RELU) {
            o.x = fmaxf(o.x, 0.0f);
            o.y = fmaxf(o.y, 0.0f);
            o.z = fmaxf(o.z, 0.0f);
            o.w = fmaxf(o.w, 0.0f);
        }
        *(float4*)(out + (size_t)(base + r0 + r) * Cc + j0) = o;
    }
}

// One wave per row; lane holds 4 channels.
__global__ void log_softmax_k(const float* __restrict__ in, float* __restrict__ out) {
    int gid  = blockIdx.x * blockDim.x + threadIdx.x;
    int row  = gid >> 6;
    int lane = threadIdx.x & 63;
    float4 v = ((const float4*)(in + (size_t)row * Cc))[lane];
    float m = fmaxf(fmaxf(v.x, v.y), fmaxf(v.z, v.w));
#pragma unroll
    for (int o = 32; o; o >>= 1) m = fmaxf(m, __shfl_xor(m, o));
    float s = expf(v.x - m) + expf(v.y - m) + expf(v.z - m) + expf(v.w - m);
#pragma unroll
    for (int o = 32; o; o >>= 1) s += __shfl_xor(s, o);
    float lse = m + logf(s);
    float4 o4;
    o4.x = v.x - lse; o4.y = v.y - lse; o4.z = v.z - lse; o4.w = v.w - lse;
    ((float4*)(out + (size_t)row * Cc))[lane] = o4;
}

extern "C" void kernel_launch(void* const* d_in, const int* in_sizes, int n_in,
                              void* d_out, int out_size, void* d_ws, size_t ws_size,
                              hipStream_t stream) {
    const float* x     = (const float*)d_in[0];
    const int*   src0  = (const int*)d_in[1];
    const int*   dst0  = (const int*)d_in[2];
    const int*   eid0  = (const int*)d_in[3];
    const int*   src1  = (const int*)d_in[4];
    const int*   dst1  = (const int*)d_in[5];
    const int*   eid1  = (const int*)d_in[6];
    const float* ew    = (const float*)d_in[7];
    const float* Wrel0 = (const float*)d_in[8];
    const float* b0    = (const float*)d_in[9];
    const float* Wroot0= (const float*)d_in[10];
    const float* Wrel1 = (const float*)d_in[11];
    const float* b1    = (const float*)d_in[12];
    const float* Wroot1= (const float*)d_in[13];

    // Workspace layout (4-byte units, 16B-aligned segments)
    char* wsb = (char*)d_ws;
    size_t o = 0;
    auto alloc = [&](size_t elems) { void* p = wsb + o; o += ((elems + 3) & ~(size_t)3) * 4; return p; };
    int*   off0  = (int*)  alloc(N1c + 1);
    int*   cur0  = (int*)  alloc(N1c);          // also degree histogram
    int*   srcs0 = (int*)  alloc(E0c);
    float* wsr0  = (float*)alloc(E0c);
    int*   off1  = (int*)  alloc(NBc + 1);
    int*   cur1  = (int*)  alloc(NBc);
    int*   srcs1 = (int*)  alloc(E1c);
    float* wsr1  = (float*)alloc(E1c);
    float* meanb = (float*)alloc((size_t)N1c * Cc);   // reused for layer1 mean
    float* h     = (float*)alloc((size_t)N1c * Cc);

    // ---- Layer 0: CSR build + gather mean ----
    hipMemsetAsync(cur0, 0, N1c * sizeof(int), stream);
    count_deg<<<(E0c + 255) / 256, 256, 0, stream>>>(dst0, cur0, E0c);
    scan_kernel<<<1, 1024, 0, stream>>>(cur0, off0, N1c);
    fill_edges<<<(E0c + 255) / 256, 256, 0, stream>>>(src0, dst0, eid0, ew, cur0, srcs0, wsr0, E0c);
    gather_mean<<<(N1c * 64) / 256, 256, 0, stream>>>(x, off0, srcs0, wsr0, meanb, N1c);

    // h = relu(mean0 @ Wrel0 + b0 + x[:N1] @ Wroot0)
    gemm_fused<true><<<N1c / 32, 256, 0, stream>>>(meanb, x, Wrel0, Wroot0, b0, h);

    // ---- Layer 1: CSR build + gather mean over h ----
    hipMemsetAsync(cur1, 0, NBc * sizeof(int), stream);
    count_deg<<<(E1c + 255) / 256, 256, 0, stream>>>(dst1, cur1, E1c);
    scan_kernel<<<1, 1024, 0, stream>>>(cur1, off1, NBc);
    fill_edges<<<(E1c + 255) / 256, 256, 0, stream>>>(src1, dst1, eid1, ew, cur1, srcs1, wsr1, E1c);
    gather_mean<<<(NBc * 64) / 256, 256, 0, stream>>>(h, off1, srcs1, wsr1, meanb, NBc);

    // out2 = mean1 @ Wrel1 + b1 + h[:NB] @ Wroot1
    float* out2 = (float*)d_out;
    gemm_fused<false><<<NBc / 32, 256, 0, stream>>>(meanb, h, Wrel1, Wroot1, b1, out2);

    // log_softmax rows
    log_softmax_k<<<(NBc * 64) / 256, 256, 0, stream>>>(out2, out2 + (size_t)NBc * Cc);
}

// Round 3
// 445.321 us; speedup vs baseline: 2.8705x; 1.3406x over previous
//
#include <hip/hip_runtime.h>
#include <cstdint>
#include <cmath>

#define N0c 247808
#define N1c 22528
#define NBc 2048
#define E0c 225280
#define E1c 20480
#define Cc  256
#define NDST (N1c + NBc)          // 24576 concatenated CSR rows
#define ETOT (E0c + E1c)          // 245760

typedef __attribute__((ext_vector_type(8))) short short8;   // 8 bf16 in 4 VGPRs
typedef __attribute__((ext_vector_type(4))) float floatx4;  // MFMA C/D frag

__device__ inline unsigned short f2bf(float f) {            // f32 -> bf16 RNE
    union { float f; unsigned u; } cv; cv.f = f;
    unsigned u = cv.u;
    u += 0x7fffu + ((u >> 16) & 1u);
    return (unsigned short)(u >> 16);
}

// ---------- CSR build: degree count over both layers ----------
__global__ void count_both(const int* __restrict__ dst0, const int* __restrict__ dst1,
                           int* __restrict__ cnt) {
    int e = blockIdx.x * blockDim.x + threadIdx.x;
    if (e < E0c) atomicAdd(&cnt[dst0[e]], 1);
    else if (e < ETOT) atomicAdd(&cnt[N1c + dst1[e - E0c]], 1);
}

// ---------- hierarchical exclusive scan over NDST (exactly 24*1024) ----------
__global__ __launch_bounds__(256) void scan_part(const int* __restrict__ in,
                                                 int* __restrict__ out,
                                                 int* __restrict__ partials) {
    __shared__ int wsum[4];
    int t = threadIdx.x, lane = t & 63, w = t >> 6;
    int base = blockIdx.x * 1024 + t * 4;
    int4 v = *(const int4*)(in + base);
    int s = v.x + v.y + v.z + v.w;
    int incl = s;
#pragma unroll
    for (int o = 1; o < 64; o <<= 1) {
        int u = __shfl_up(incl, o);
        if (lane >= o) incl += u;
    }
    if (lane == 63) wsum[w] = incl;
    __syncthreads();
    int woff = 0;
    for (int j = 0; j < w; j++) woff += wsum[j];
    int excl = woff + incl - s;
    int4 o4;
    o4.x = excl; excl += v.x;
    o4.y = excl; excl += v.y;
    o4.z = excl; excl += v.z;
    o4.w = excl; excl += v.w;
    *(int4*)(out + base) = o4;
    if (t == 255) partials[blockIdx.x] = woff + incl;
}

__global__ void scan_partials(int* __restrict__ partials, int* __restrict__ total, int np) {
    int t = threadIdx.x;
    int v = (t < np) ? partials[t] : 0;
    int incl = v;
#pragma unroll
    for (int o = 1; o < 64; o <<= 1) {
        int u = __shfl_up(incl, o);
        if (t >= o) incl += u;
    }
    if (t < np) partials[t] = incl - v;   // exclusive
    if (t == 63) total[0] = incl;         // off[NDST]
}

__global__ __launch_bounds__(256) void scan_add(int* __restrict__ off, int* __restrict__ cur,
                                                const int* __restrict__ partials) {
    int t = threadIdx.x;
    int base = blockIdx.x * 1024 + t * 4;
    int p = partials[blockIdx.x];
    int4 v = *(const int4*)(off + base);
    v.x += p; v.y += p; v.z += p; v.w += p;
    *(int4*)(off + base) = v;
    *(int4*)(cur + base) = v;
}

// ---------- CSR fill: both layers into concatenated slot arrays ----------
__global__ void fill_both(const int* __restrict__ src0, const int* __restrict__ dst0,
                          const int* __restrict__ eid0,
                          const int* __restrict__ src1, const int* __restrict__ dst1,
                          const int* __restrict__ eid1,
                          const float* __restrict__ ew,
                          int* __restrict__ cur, int* __restrict__ srcs,
                          float* __restrict__ wsr) {
    int e = blockIdx.x * blockDim.x + threadIdx.x;
    if (e < E0c) {
        int p = atomicAdd(&cur[dst0[e]], 1);
        srcs[p] = src0[e];
        wsr[p] = ew[eid0[e]];
    } else if (e < ETOT) {
        int i = e - E0c;
        int p = atomicAdd(&cur[N1c + dst1[i]], 1);
        srcs[p] = src1[i];
        wsr[p] = ew[eid1[i]];
    }
}

// ---------- pack W = [Wrel;Wroot] (K=512,N=256) into B-fragment order, bf16 ----------
// layout: [nt(16)][kt(16)][lane(64)][8 bf16]; lane holds B[k=kt*32+(lane>>4)*8+j][n=nt*16+(lane&15)]
__global__ void pack_W(const float* __restrict__ Wrel0, const float* __restrict__ Wroot0,
                       const float* __restrict__ Wrel1, const float* __restrict__ Wroot1,
                       short* __restrict__ Wp0, short* __restrict__ Wp1) {
    int gid = blockIdx.x * blockDim.x + threadIdx.x;   // 2*16*16*64 = 32768
    int lane = gid & 63;
    int kt = (gid >> 6) & 15;
    int nt = (gid >> 10) & 15;
    int layer = gid >> 14;
    const float* Wrel  = layer ? Wrel1  : Wrel0;
    const float* Wroot = layer ? Wroot1 : Wroot0;
    short* Wp = layer ? Wp1 : Wp0;
    int nn = nt * 16 + (lane & 15);
    int kb = kt * 32 + (lane >> 4) * 8;
    unsigned short frag[8];
#pragma unroll
    for (int j = 0; j < 8; j++) {
        int k = kb + j;
        float f = (k < 256) ? Wrel[k * 256 + nn] : Wroot[(k - 256) * 256 + nn];
        frag[j] = f2bf(f);
    }
    short8 v;
#pragma unroll
    for (int j = 0; j < 8; j++) v[j] = (short)frag[j];
    *(short8*)(Wp + (((size_t)nt * 16 + kt) * 64 + lane) * 8) = v;
}

// ---------- convert x[:N1] rows into bf16 root half of A0 ----------
__global__ __launch_bounds__(256) void convert_root(const float* __restrict__ x,
                                                    short* __restrict__ A0) {
    int gid = blockIdx.x * blockDim.x + threadIdx.x;
    int row = gid >> 6, lane = gid & 63;
    float4 v = *(const float4*)(x + (size_t)row * Cc + lane * 4);
    ushort4 o;
    o.x = f2bf(v.x); o.y = f2bf(v.y); o.z = f2bf(v.z); o.w = f2bf(v.w);
    *(ushort4*)(A0 + (size_t)row * 512 + 256 + lane * 4) = o;
}

// ---------- gather-side mean, writes bf16 into mean half of A ----------
__global__ __launch_bounds__(256) void gather_mean_bf16(const float* __restrict__ feat,
                                                        const int* __restrict__ off,
                                                        const int* __restrict__ srcs,
                                                        const float* __restrict__ wsr,
                                                        short* __restrict__ outA,
                                                        int baseRow, int nrows) {
    int wid  = (blockIdx.x * blockDim.x + threadIdx.x) >> 6;
    int lane = threadIdx.x & 63;
    if (wid >= nrows) return;
    int crow = baseRow + wid;
    int s = off[crow], e = off[crow + 1];
    float4 acc = make_float4(0.f, 0.f, 0.f, 0.f);
    int i = s;
    for (; i + 1 < e; i += 2) {
        int   s0 = srcs[i], s1 = srcs[i + 1];
        float w0 = wsr[i],  w1 = wsr[i + 1];
        float4 v0 = ((const float4*)(feat + (size_t)s0 * Cc))[lane];
        float4 v1 = ((const float4*)(feat + (size_t)s1 * Cc))[lane];
        acc.x += w0 * v0.x + w1 * v1.x;
        acc.y += w0 * v0.y + w1 * v1.y;
        acc.z += w0 * v0.z + w1 * v1.z;
        acc.w += w0 * v0.w + w1 * v1.w;
    }
    if (i < e) {
        int sid = srcs[i];
        float w = wsr[i];
        float4 v = ((const float4*)(feat + (size_t)sid * Cc))[lane];
        acc.x += w * v.x; acc.y += w * v.y; acc.z += w * v.z; acc.w += w * v.w;
    }
    float inv = 1.0f / fmaxf((float)(e - s), 1.0f);
    ushort4 o;
    o.x = f2bf(acc.x * inv); o.y = f2bf(acc.y * inv);
    o.z = f2bf(acc.z * inv); o.w = f2bf(acc.w * inv);
    *(ushort4*)(outA + (size_t)wid * 512 + lane * 4) = o;
}

// ---------- MFMA GEMM: out[M x 256] = A[M x 512]bf16 @ Wp + bias ----------
// block: 256 thr = 4 waves; 32 rows x 256 cols per block; wave w -> col tiles 4w..4w+3
template <bool RELU, bool EXTRA>
__global__ __launch_bounds__(256) void gemm_mfma(const short* __restrict__ A,
                                                 const short* __restrict__ Wp,
                                                 const float* __restrict__ bias,
                                                 float* __restrict__ out,
                                                 short* __restrict__ extra) {
    __shared__ short As[32 * 520];   // pad 512->520 bf16: staging & frag reads at bank floor
    int t = threadIdx.x;
    int base = blockIdx.x * 32;
#pragma unroll
    for (int it = 0; it < 8; it++) {
        int idx = it * 256 + t;
        int row = idx >> 6, c = idx & 63;
        short8 v = *(const short8*)(A + (size_t)(base + row) * 512 + c * 8);
        *(short8*)(&As[row * 520 + c * 8]) = v;
    }
    __syncthreads();

    int lane = t & 63, w = t >> 6;
    int l15 = lane & 15, lq = lane >> 4;
    floatx4 acc[2][4];
#pragma unroll
    for (int rt = 0; rt < 2; rt++)
#pragma unroll
        for (int ct = 0; ct < 4; ct++) acc[rt][ct] = (floatx4){0.f, 0.f, 0.f, 0.f};

    for (int kt = 0; kt < 16; kt++) {
        short8 a0 = *(const short8*)(&As[l15 * 520 + kt * 32 + lq * 8]);
        short8 a1 = *(const short8*)(&As[(16 + l15) * 520 + kt * 32 + lq * 8]);
#pragma unroll
        for (int ct = 0; ct < 4; ct++) {
            int nt = w * 4 + ct;
            short8 b = *(const short8*)(Wp + (((size_t)nt * 16 + kt) * 64 + lane) * 8);
            acc[0][ct] = __builtin_amdgcn_mfma_f32_16x16x32_bf16(a0, b, acc[0][ct], 0, 0, 0);
            acc[1][ct] = __builtin_amdgcn_mfma_f32_16x16x32_bf16(a1, b, acc[1][ct], 0, 0, 0);
        }
    }

#pragma unroll
    for (int rt = 0; rt < 2; rt++)
#pragma unroll
        for (int ct = 0; ct < 4; ct++) {
            int col = (w * 4 + ct) * 16 + l15;
            float bv = bias[col];
#pragma unroll
            for (int r = 0; r < 4; r++) {
                int row = base + rt * 16 + lq * 4 + r;
                float val = acc[rt][ct][r] + bv;
                if (RELU) val = fmaxf(val, 0.f);
                out[(size_t)row * Cc + col] = val;
                if (EXTRA) {
                    if (row < NBc) extra[(size_t)row * 512 + 256 + col] = (short)f2bf(val);
                }
            }
        }
}

// ---------- log_softmax: one wave per row ----------
__global__ void log_softmax_k(const float* __restrict__ in, float* __restrict__ out) {
    int gid  = blockIdx.x * blockDim.x + threadIdx.x;
    int row  = gid >> 6;
    int lane = threadIdx.x & 63;
    float4 v = ((const float4*)(in + (size_t)row * Cc))[lane];
    float m = fmaxf(fmaxf(v.x, v.y), fmaxf(v.z, v.w));
#pragma unroll
    for (int o = 32; o; o >>= 1) m = fmaxf(m, __shfl_xor(m, o));
    float s = expf(v.x - m) + expf(v.y - m) + expf(v.z - m) + expf(v.w - m);
#pragma unroll
    for (int o = 32; o; o >>= 1) s += __shfl_xor(s, o);
    float lse = m + logf(s);
    float4 o4;
    o4.x = v.x - lse; o4.y = v.y - lse; o4.z = v.z - lse; o4.w = v.w - lse;
    ((float4*)(out + (size_t)row * Cc))[lane] = o4;
}

extern "C" void kernel_launch(void* const* d_in, const int* in_sizes, int n_in,
                              void* d_out, int out_size, void* d_ws, size_t ws_size,
                              hipStream_t stream) {
    const float* x     = (const float*)d_in[0];
    const int*   src0  = (const int*)d_in[1];
    const int*   dst0  = (const int*)d_in[2];
    const int*   eid0  = (const int*)d_in[3];
    const int*   src1  = (const int*)d_in[4];
    const int*   dst1  = (const int*)d_in[5];
    const int*   eid1  = (const int*)d_in[6];
    const float* ew    = (const float*)d_in[7];
    const float* Wrel0 = (const float*)d_in[8];
    const float* b0    = (const float*)d_in[9];
    const float* Wroot0= (const float*)d_in[10];
    const float* Wrel1 = (const float*)d_in[11];
    const float* b1    = (const float*)d_in[12];
    const float* Wroot1= (const float*)d_in[13];

    char* wsb = (char*)d_ws;
    size_t o = 0;
    auto alloc = [&](size_t bytes) { void* p = wsb + o; o += (bytes + 15) & ~(size_t)15; return p; };
    int*   off   = (int*)  alloc((NDST + 1) * 4);
    int*   cnt   = (int*)  alloc(NDST * 4);          // degree, then "cur"
    int*   srcs  = (int*)  alloc(ETOT * 4);
    float* wsr   = (float*)alloc(ETOT * 4);
    int*   parts = (int*)  alloc(64 * 4);
    short* Wp0   = (short*)alloc(16 * 16 * 64 * 8 * 2);
    short* Wp1   = (short*)alloc(16 * 16 * 64 * 8 * 2);
    short* A0    = (short*)alloc((size_t)N1c * 512 * 2);
    short* A1    = (short*)alloc((size_t)NBc * 512 * 2);
    float* h     = (float*)alloc((size_t)N1c * Cc * 4);

    // ---- CSR build (both layers, concatenated) ----
    hipMemsetAsync(cnt, 0, NDST * sizeof(int), stream);
    count_both<<<ETOT / 256, 256, 0, stream>>>(dst0, dst1, cnt);
    scan_part<<<NDST / 1024, 256, 0, stream>>>(cnt, off, parts);
    scan_partials<<<1, 64, 0, stream>>>(parts, off + NDST, NDST / 1024);
    scan_add<<<NDST / 1024, 256, 0, stream>>>(off, cnt, parts);   // cnt becomes cur
    fill_both<<<ETOT / 256, 256, 0, stream>>>(src0, dst0, eid0, src1, dst1, eid1,
                                              ew, cnt, srcs, wsr);

    // ---- weight packing + root conversion (independent) ----
    pack_W<<<32768 / 256, 256, 0, stream>>>(Wrel0, Wroot0, Wrel1, Wroot1, Wp0, Wp1);
    convert_root<<<(N1c * 64) / 256, 256, 0, stream>>>(x, A0);

    // ---- layer 0 ----
    gather_mean_bf16<<<(N1c * 64) / 256, 256, 0, stream>>>(x, off, srcs, wsr, A0, 0, N1c);
    gemm_mfma<true, true><<<N1c / 32, 256, 0, stream>>>(A0, Wp0, b0, h, A1);

    // ---- layer 1 ----
    gather_mean_bf16<<<(NBc * 64) / 256, 256, 0, stream>>>(h, off, srcs, wsr, A1, N1c, NBc);
    float* out2 = (float*)d_out;
    gemm_mfma<false, false><<<NBc / 32, 256, 0, stream>>>(A1, Wp1, b1, out2, nullptr);

    // ---- log_softmax ----
    log_softmax_k<<<(NBc * 64) / 256, 256, 0, stream>>>(out2, out2 + (size_t)NBc * Cc);
}

// Round 4
// 442.536 us; speedup vs baseline: 2.8885x; 1.0063x over previous
//
#include <hip/hip_runtime.h>
#include <cstdint>
#include <cmath>

#define N0c 247808
#define N1c 22528
#define NBc 2048
#define E0c 225280
#define E1c 20480
#define Cc  256
#define NDST (N1c + NBc)          // 24576 = 24*1024 concatenated CSR rows
#define ETOT (E0c + E1c)          // 245760

typedef __attribute__((ext_vector_type(8))) short short8;   // 8 bf16 in 4 VGPRs
typedef __attribute__((ext_vector_type(4))) float floatx4;  // MFMA C/D frag

__device__ inline unsigned short f2bf(float f) {            // f32 -> bf16 RNE
    union { float f; unsigned u; } cv; cv.f = f;
    unsigned u = cv.u;
    u += 0x7fffu + ((u >> 16) & 1u);
    return (unsigned short)(u >> 16);
}

// ---------- fused prep: degree count (blocks 0..959) + W pack (960..1087) ----------
// pack layout: [nt(16)][kt(16)][lane(64)][8 bf16]; lane holds
// B[k=kt*32+(lane>>4)*8+j][n=nt*16+(lane&15)], W = [Wrel;Wroot] (K=512)
__global__ __launch_bounds__(256) void prep_kernel(
    const int* __restrict__ dst0, const int* __restrict__ dst1, int* __restrict__ cnt,
    const float* __restrict__ Wrel0, const float* __restrict__ Wroot0,
    const float* __restrict__ Wrel1, const float* __restrict__ Wroot1,
    short* __restrict__ Wp0, short* __restrict__ Wp1) {
    int b = blockIdx.x;
    if (b < ETOT / 256) {
        int e = b * 256 + threadIdx.x;
        if (e < E0c) atomicAdd(&cnt[dst0[e]], 1);
        else         atomicAdd(&cnt[N1c + dst1[e - E0c]], 1);
    } else {
        int gid = (b - ETOT / 256) * 256 + threadIdx.x;   // 0..32767
        int lane = gid & 63;
        int kt = (gid >> 6) & 15;
        int nt = (gid >> 10) & 15;
        int layer = gid >> 14;
        const float* Wrel  = layer ? Wrel1  : Wrel0;
        const float* Wroot = layer ? Wroot1 : Wroot0;
        short* Wp = layer ? Wp1 : Wp0;
        int nn = nt * 16 + (lane & 15);
        int kb = kt * 32 + (lane >> 4) * 8;
        short8 v;
#pragma unroll
        for (int j = 0; j < 8; j++) {
            int k = kb + j;
            float f = (k < 256) ? Wrel[k * 256 + nn] : Wroot[(k - 256) * 256 + nn];
            v[j] = (short)f2bf(f);
        }
        *(short8*)(Wp + (((size_t)nt * 16 + kt) * 64 + lane) * 8) = v;
    }
}

// ---------- scan stage 1: per-1024-chunk exclusive scan + chunk totals ----------
__global__ __launch_bounds__(256) void scan_part(const int* __restrict__ in,
                                                 int* __restrict__ out,
                                                 int* __restrict__ partials) {
    __shared__ int wsum[4];
    int t = threadIdx.x, lane = t & 63, w = t >> 6;
    int base = blockIdx.x * 1024 + t * 4;
    int4 v = *(const int4*)(in + base);
    int s = v.x + v.y + v.z + v.w;
    int incl = s;
#pragma unroll
    for (int o = 1; o < 64; o <<= 1) {
        int u = __shfl_up(incl, o);
        if (lane >= o) incl += u;
    }
    if (lane == 63) wsum[w] = incl;
    __syncthreads();
    int woff = 0;
    for (int j = 0; j < w; j++) woff += wsum[j];
    int excl = woff + incl - s;
    int4 o4;
    o4.x = excl; excl += v.x;
    o4.y = excl; excl += v.y;
    o4.z = excl; excl += v.z;
    o4.w = excl; excl += v.w;
    *(int4*)(out + base) = o4;
    if (t == 255) partials[blockIdx.x] = woff + incl;
}

// ---------- scan stage 2: re-scan 24 partials in-wave, add, emit cur & total ----------
__global__ __launch_bounds__(256) void scan_add(int* __restrict__ off, int* __restrict__ cur,
                                                const int* __restrict__ partials) {
    __shared__ int pfx_s;
    int t = threadIdx.x;
    if (t < 32) {
        int v = (t < NDST / 1024) ? partials[t] : 0;
        int incl = v;
#pragma unroll
        for (int o = 1; o < 32; o <<= 1) {
            int u = __shfl_up(incl, o);
            if (t >= o) incl += u;
        }
        if (t == (int)blockIdx.x) pfx_s = incl - v;       // exclusive prefix for this block
        if (blockIdx.x == 0 && t == NDST / 1024 - 1) off[NDST] = incl;  // grand total
    }
    __syncthreads();
    int p = pfx_s;
    int base = blockIdx.x * 1024 + t * 4;
    int4 v = *(const int4*)(off + base);
    v.x += p; v.y += p; v.z += p; v.w += p;
    *(int4*)(off + base) = v;
    *(int4*)(cur + base) = v;
}

// ---------- CSR fill: both layers into concatenated slot arrays ----------
__global__ void fill_both(const int* __restrict__ src0, const int* __restrict__ dst0,
                          const int* __restrict__ eid0,
                          const int* __restrict__ src1, const int* __restrict__ dst1,
                          const int* __restrict__ eid1,
                          const float* __restrict__ ew,
                          int* __restrict__ cur, int* __restrict__ srcs,
                          float* __restrict__ wsr) {
    int e = blockIdx.x * blockDim.x + threadIdx.x;
    if (e < E0c) {
        int p = atomicAdd(&cur[dst0[e]], 1);
        srcs[p] = src0[e];
        wsr[p] = ew[eid0[e]];
    } else if (e < ETOT) {
        int i = e - E0c;
        int p = atomicAdd(&cur[N1c + dst1[i]], 1);
        srcs[p] = src1[i];
        wsr[p] = ew[eid1[i]];
    }
}

// ---------- gather-side mean (one wave per dst row), bf16 out; optional root fill ----------
template <bool ROOT>
__global__ __launch_bounds__(256) void gather_mean_bf16(const float* __restrict__ feat,
                                                        const int* __restrict__ off,
                                                        const int* __restrict__ srcs,
                                                        const float* __restrict__ wsr,
                                                        short* __restrict__ outA,
                                                        int baseRow, int nrows) {
    int wid  = (blockIdx.x * blockDim.x + threadIdx.x) >> 6;
    int lane = threadIdx.x & 63;
    if (wid >= nrows) return;
    int crow = baseRow + wid;
    int s = off[crow], e = off[crow + 1];
    float4 acc = make_float4(0.f, 0.f, 0.f, 0.f);
    int i = s;
    for (; i + 3 < e; i += 4) {   // 4 row loads in flight
        int   s0 = srcs[i],     s1 = srcs[i + 1], s2 = srcs[i + 2], s3 = srcs[i + 3];
        float w0 = wsr[i],      w1 = wsr[i + 1],  w2 = wsr[i + 2],  w3 = wsr[i + 3];
        float4 v0 = ((const float4*)(feat + (size_t)s0 * Cc))[lane];
        float4 v1 = ((const float4*)(feat + (size_t)s1 * Cc))[lane];
        float4 v2 = ((const float4*)(feat + (size_t)s2 * Cc))[lane];
        float4 v3 = ((const float4*)(feat + (size_t)s3 * Cc))[lane];
        acc.x += w0 * v0.x + w1 * v1.x + w2 * v2.x + w3 * v3.x;
        acc.y += w0 * v0.y + w1 * v1.y + w2 * v2.y + w3 * v3.y;
        acc.z += w0 * v0.z + w1 * v1.z + w2 * v2.z + w3 * v3.z;
        acc.w += w0 * v0.w + w1 * v1.w + w2 * v2.w + w3 * v3.w;
    }
    for (; i < e; i++) {
        int sid = srcs[i];
        float w = wsr[i];
        float4 v = ((const float4*)(feat + (size_t)sid * Cc))[lane];
        acc.x += w * v.x; acc.y += w * v.y; acc.z += w * v.z; acc.w += w * v.w;
    }
    float inv = 1.0f / fmaxf((float)(e - s), 1.0f);
    ushort4 o;
    o.x = f2bf(acc.x * inv); o.y = f2bf(acc.y * inv);
    o.z = f2bf(acc.z * inv); o.w = f2bf(acc.w * inv);
    *(ushort4*)(outA + (size_t)wid * 512 + lane * 4) = o;
    if (ROOT) {   // fused root-half conversion: x[crow] -> bf16 (crow==wid when baseRow==0)
        float4 r = ((const float4*)(feat + (size_t)crow * Cc))[lane];
        ushort4 ro;
        ro.x = f2bf(r.x); ro.y = f2bf(r.y); ro.z = f2bf(r.z); ro.w = f2bf(r.w);
        *(ushort4*)(outA + (size_t)wid * 512 + 256 + lane * 4) = ro;
    }
}

// ---------- MFMA GEMM: out[M x 256] = A[M x 512]bf16 @ Wp + bias ----------
// 256 thr = 4 waves; 32 rows x 256 cols per block; wave w -> col tiles 4w..4w+3.
// EXTRA: also write bf16 into A1 root half for rows < NBc.
// SMAX: fused log_softmax epilogue via LDS (block owns full rows); out1 gets log-probs.
template <bool RELU, bool EXTRA, bool SMAX>
__global__ __launch_bounds__(256) void gemm_mfma(const short* __restrict__ A,
                                                 const short* __restrict__ Wp,
                                                 const float* __restrict__ bias,
                                                 float* __restrict__ out,
                                                 short* __restrict__ extra,
                                                 float* __restrict__ out1) {
    __shared__ short As[32 * 520];   // pad 512->520: staging & frag reads at bank floor
    int t = threadIdx.x;
    int base = blockIdx.x * 32;
#pragma unroll
    for (int it = 0; it < 8; it++) {
        int idx = it * 256 + t;
        int row = idx >> 6, c = idx & 63;
        short8 v = *(const short8*)(A + (size_t)(base + row) * 512 + c * 8);
        *(short8*)(&As[row * 520 + c * 8]) = v;
    }
    __syncthreads();

    int lane = t & 63, w = t >> 6;
    int l15 = lane & 15, lq = lane >> 4;
    floatx4 acc[2][4];
#pragma unroll
    for (int rt = 0; rt < 2; rt++)
#pragma unroll
        for (int ct = 0; ct < 4; ct++) acc[rt][ct] = (floatx4){0.f, 0.f, 0.f, 0.f};

    for (int kt = 0; kt < 16; kt++) {
        short8 a0 = *(const short8*)(&As[l15 * 520 + kt * 32 + lq * 8]);
        short8 a1 = *(const short8*)(&As[(16 + l15) * 520 + kt * 32 + lq * 8]);
#pragma unroll
        for (int ct = 0; ct < 4; ct++) {
            int nt = w * 4 + ct;
            short8 b = *(const short8*)(Wp + (((size_t)nt * 16 + kt) * 64 + lane) * 8);
            acc[0][ct] = __builtin_amdgcn_mfma_f32_16x16x32_bf16(a0, b, acc[0][ct], 0, 0, 0);
            acc[1][ct] = __builtin_amdgcn_mfma_f32_16x16x32_bf16(a1, b, acc[1][ct], 0, 0, 0);
        }
    }

    float* Ls = (float*)As;          // alias A-tile LDS for softmax buffer (32 x 260 f32)
    if (SMAX) __syncthreads();       // all As reads done before overwrite

#pragma unroll
    for (int rt = 0; rt < 2; rt++)
#pragma unroll
        for (int ct = 0; ct < 4; ct++) {
            int col = (w * 4 + ct) * 16 + l15;
            float bv = bias[col];
#pragma unroll
            for (int r = 0; r < 4; r++) {
                int rl = rt * 16 + lq * 4 + r;
                int row = base + rl;
                float val = acc[rt][ct][r] + bv;
                if (RELU) val = fmaxf(val, 0.f);
                out[(size_t)row * Cc + col] = val;
                if (EXTRA) {
                    if (row < NBc) extra[(size_t)row * 512 + 256 + col] = (short)f2bf(val);
                }
                if (SMAX) Ls[rl * 260 + col] = val;
            }
        }

    if (SMAX) {
        __syncthreads();
        for (int rr = 0; rr < 8; rr++) {
            int rl = w * 8 + rr;
            float4 v = *(const float4*)(Ls + rl * 260 + lane * 4);
            float m = fmaxf(fmaxf(v.x, v.y), fmaxf(v.z, v.w));
#pragma unroll
            for (int o = 32; o; o >>= 1) m = fmaxf(m, __shfl_xor(m, o));
            float s = expf(v.x - m) + expf(v.y - m) + expf(v.z - m) + expf(v.w - m);
#pragma unroll
            for (int o = 32; o; o >>= 1) s += __shfl_xor(s, o);
            float lse = m + logf(s);
            float4 o4;
            o4.x = v.x - lse; o4.y = v.y - lse; o4.z = v.z - lse; o4.w = v.w - lse;
            *(float4*)(out1 + (size_t)(base + rl) * Cc + lane * 4) = o4;
        }
    }
}

extern "C" void kernel_launch(void* const* d_in, const int* in_sizes, int n_in,
                              void* d_out, int out_size, void* d_ws, size_t ws_size,
                              hipStream_t stream) {
    const float* x     = (const float*)d_in[0];
    const int*   src0  = (const int*)d_in[1];
    const int*   dst0  = (const int*)d_in[2];
    const int*   eid0  = (const int*)d_in[3];
    const int*   src1  = (const int*)d_in[4];
    const int*   dst1  = (const int*)d_in[5];
    const int*   eid1  = (const int*)d_in[6];
    const float* ew    = (const float*)d_in[7];
    const float* Wrel0 = (const float*)d_in[8];
    const float* b0    = (const float*)d_in[9];
    const float* Wroot0= (const float*)d_in[10];
    const float* Wrel1 = (const float*)d_in[11];
    const float* b1    = (const float*)d_in[12];
    const float* Wroot1= (const float*)d_in[13];

    char* wsb = (char*)d_ws;
    size_t o = 0;
    auto alloc = [&](size_t bytes) { void* p = wsb + o; o += (bytes + 15) & ~(size_t)15; return p; };
    int*   off   = (int*)  alloc((NDST + 1) * 4);
    int*   cnt   = (int*)  alloc(NDST * 4);          // degree, then "cur"
    int*   srcs  = (int*)  alloc(ETOT * 4);
    float* wsr   = (float*)alloc(ETOT * 4);
    int*   parts = (int*)  alloc(64 * 4);
    short* Wp0   = (short*)alloc(16 * 16 * 64 * 8 * 2);
    short* Wp1   = (short*)alloc(16 * 16 * 64 * 8 * 2);
    short* A0    = (short*)alloc((size_t)N1c * 512 * 2);
    short* A1    = (short*)alloc((size_t)NBc * 512 * 2);
    float* h     = (float*)alloc((size_t)N1c * Cc * 4);

    // ---- CSR build + W pack ----
    hipMemsetAsync(cnt, 0, NDST * sizeof(int), stream);
    prep_kernel<<<ETOT / 256 + 128, 256, 0, stream>>>(dst0, dst1, cnt,
                                                      Wrel0, Wroot0, Wrel1, Wroot1, Wp0, Wp1);
    scan_part<<<NDST / 1024, 256, 0, stream>>>(cnt, off, parts);
    scan_add<<<NDST / 1024, 256, 0, stream>>>(off, cnt, parts);   // cnt becomes cur
    fill_both<<<ETOT / 256, 256, 0, stream>>>(src0, dst0, eid0, src1, dst1, eid1,
                                              ew, cnt, srcs, wsr);

    // ---- layer 0: gather (mean + fused root convert) then GEMM ----
    gather_mean_bf16<true><<<(N1c * 64) / 256, 256, 0, stream>>>(x, off, srcs, wsr, A0, 0, N1c);
    gemm_mfma<true, true, false><<<N1c / 32, 256, 0, stream>>>(A0, Wp0, b0, h, A1, nullptr);

    // ---- layer 1: gather then GEMM with fused log_softmax ----
    gather_mean_bf16<false><<<(NBc * 64) / 256, 256, 0, stream>>>(h, off, srcs, wsr, A1, N1c, NBc);
    float* out2 = (float*)d_out;
    gemm_mfma<false, false, true><<<NBc / 32, 256, 0, stream>>>(A1, Wp1, b1, out2, nullptr,
                                                                out2 + (size_t)NBc * Cc);
}